// Round 1
// baseline (244.457 us; speedup 1.0000x reference)
//
#include <hip/hip_runtime.h>

#define NB 4
#define C 64
#define H 256
#define W 256
#define HW (H * W)
#define NH 10
#define KK 5
#define NBINS 1024
#define CHUNK 256
#define NCHUNK (HW / CHUNK)

// ---------------- per-batch sum of squares (partials per block) ----------------
// grid = NB*256 blocks; block bid: batch = bid>>8, chunk = bid&255 (4096 float4 each)
__global__ __launch_bounds__(256) void sumsq_kernel(const float* __restrict__ x,
                                                    float* __restrict__ part) {
    int bid = blockIdx.x;
    int b = bid >> 8, ch = bid & 255;
    const float4* p = reinterpret_cast<const float4*>(x + (size_t)b * C * HW) + (size_t)ch * 4096;
    float s = 0.f;
    for (int i = threadIdx.x; i < 4096; i += 256) {
        float4 v = p[i];
        s += v.x * v.x + v.y * v.y + v.z * v.z + v.w * v.w;
    }
    __shared__ float red[256];
    red[threadIdx.x] = s;
    __syncthreads();
    for (int off = 128; off; off >>= 1) {
        if (threadIdx.x < off) red[threadIdx.x] += red[threadIdx.x + off];
        __syncthreads();
    }
    if (threadIdx.x == 0) part[bid] = red[0];
}

// ---------------- reduce partials per batch + argmax -> best ----------------
__global__ __launch_bounds__(1024) void reduce_argmax_kernel(const float* __restrict__ part,
                                                             int per_batch,
                                                             int* __restrict__ best) {
    __shared__ float sm[1024];
    float norms[NB];
    int t = threadIdx.x;
    for (int b = 0; b < NB; b++) {
        float s = 0.f;
        for (int i = t; i < per_batch; i += 1024) s += part[(size_t)b * per_batch + i];
        sm[t] = s;
        __syncthreads();
        for (int off = 512; off; off >>= 1) {
            if (t < off) sm[t] += sm[t + off];
            __syncthreads();
        }
        norms[b] = sm[0];
        __syncthreads();
    }
    if (t == 0) {
        int bb = 0;
        float m = norms[0];
        for (int i = 1; i < NB; i++)
            if (norms[i] > m) { m = norms[i]; bb = i; }
        *best = bb;
    }
}

// ---------------- LSH codes + transpose of best plane + per-chunk histogram ----------------
// grid = 256 blocks x 256 threads, one pixel per thread
__global__ __launch_bounds__(256) void hash_kernel(const float* __restrict__ Xall,
                                                   const int* __restrict__ bestp,
                                                   const float* __restrict__ rvecs,
                                                   float* __restrict__ xT,
                                                   int* __restrict__ dec,
                                                   int* __restrict__ hist) {
    __shared__ float tile[CHUNK][33];  // half the channels at a time, +1 pad
    __shared__ float rv[NH * C];
    __shared__ int lhist[NBINS];
    int t = threadIdx.x;
    for (int i = t; i < NH * C; i += 256) rv[i] = rvecs[i];
    for (int i = t; i < NBINS; i += 256) lhist[i] = 0;
    int best = *bestp;
    const float* X = Xall + (size_t)best * C * HW;
    int p0 = blockIdx.x * CHUNK;
    float acc[NH];
#pragma unroll
    for (int h2 = 0; h2 < NH; h2++) acc[h2] = 0.f;

    for (int half = 0; half < 2; half++) {
        __syncthreads();
        for (int c = 0; c < 32; c++) tile[t][c] = X[(size_t)(half * 32 + c) * HW + p0 + t];
        __syncthreads();
        float* xrow = xT + (size_t)(p0 + t) * C + half * 32;
        for (int c = 0; c < 32; c += 4) {
            float4 v = make_float4(tile[t][c], tile[t][c + 1], tile[t][c + 2], tile[t][c + 3]);
            *reinterpret_cast<float4*>(xrow + c) = v;
#pragma unroll
            for (int h2 = 0; h2 < NH; h2++) {
                const float* r = rv + h2 * C + half * 32 + c;
                acc[h2] += v.x * r[0] + v.y * r[1] + v.z * r[2] + v.w * r[3];
            }
        }
    }
    int d = 0;
#pragma unroll
    for (int h2 = 0; h2 < NH; h2++) d |= (acc[h2] > 0.f) ? (1 << h2) : 0;
    dec[p0 + t] = d;
    atomicAdd(&lhist[d], 1);
    __syncthreads();
    for (int i = t; i < NBINS; i += 256) hist[(size_t)blockIdx.x * NBINS + i] = lhist[i];
}

// ---------------- per-bin chunk prefix + global bin offsets ----------------
__global__ __launch_bounds__(1024) void scan_kernel(int* __restrict__ hist,
                                                    int* __restrict__ binoff) {
    int b = threadIdx.x;  // one bin per thread
    int run = 0;
    for (int ch = 0; ch < NCHUNK; ch++) {
        int v = hist[(size_t)ch * NBINS + b];
        hist[(size_t)ch * NBINS + b] = run;
        run += v;
    }
    __shared__ int tot[NBINS];
    tot[b] = run;
    __syncthreads();
    for (int off = 1; off < NBINS; off <<= 1) {
        int v = (b >= off) ? tot[b - off] : 0;
        __syncthreads();
        tot[b] += v;
        __syncthreads();
    }
    binoff[b] = tot[b] - run;  // exclusive
}

// ---------------- stable scatter: order[sorted_pos] = original pixel ----------------
__global__ __launch_bounds__(256) void scatter_kernel(const int* __restrict__ dec,
                                                      const int* __restrict__ hist,
                                                      const int* __restrict__ binoff,
                                                      int* __restrict__ order) {
    __shared__ int keys[CHUNK];
    int p0 = blockIdx.x * CHUNK;
    int t = threadIdx.x;
    int k = dec[p0 + t];
    keys[t] = k;
    __syncthreads();
    int r = 0;
    for (int j = 0; j < t; j++) r += (keys[j] == k) ? 1 : 0;
    int dst = binoff[k] + hist[(size_t)blockIdx.x * NBINS + k] + r;
    order[dst] = p0 + t;
}

// ---------------- filter: sigmoid(conv_w @ bg), bg = sorted best plane ----------------
__global__ __launch_bounds__(256) void filt_kernel(const float* __restrict__ xT,
                                                   const int* __restrict__ order,
                                                   const float* __restrict__ cwg,
                                                   float* __restrict__ filt) {
    __shared__ float cw[NH * C];
    int t = threadIdx.x;
    for (int i = t; i < NH * C; i += 256) cw[i] = cwg[i];
    __syncthreads();
    int p = blockIdx.x * 256 + t;
    int orig = order[p];
    const float4* row = reinterpret_cast<const float4*>(xT + (size_t)orig * C);
    float acc[NH];
#pragma unroll
    for (int h2 = 0; h2 < NH; h2++) acc[h2] = 0.f;
#pragma unroll
    for (int q = 0; q < 16; q++) {
        float4 v = row[q];
#pragma unroll
        for (int h2 = 0; h2 < NH; h2++) {
            const float* r = cw + h2 * C + q * 4;
            acc[h2] += v.x * r[0] + v.y * r[1] + v.z * r[2] + v.w * r[3];
        }
    }
#pragma unroll
    for (int h2 = 0; h2 < NH; h2++) filt[(size_t)h2 * HW + p] = 1.f / (1.f + expf(-acc[h2]));
}

// ---------------- horizontal strip conv + sumsq partials for pass-2 norms ----------------
// grid = NB*C*H blocks (one row each), 256 threads (one x each)
__global__ __launch_bounds__(256) void convh_kernel(const float* __restrict__ X,
                                                    const float* __restrict__ filt,
                                                    float* __restrict__ out1,
                                                    float* __restrict__ part) {
    int bid = blockIdx.x;
    int y = bid & (H - 1);
    int c = (bid >> 8) & (C - 1);
    int n = bid >> 14;
    int g = c >> 5;
    int t = threadIdx.x;
    __shared__ float row[W + 4];
    const float* src = X + (((size_t)n * C + c) * H + y) * W;
    row[t + 2] = src[t];
    if (t < 2) {
        row[1 - t] = src[t + 1];          // row[1]=src[1], row[0]=src[2]
        row[W + 2 + t] = src[W - 2 - t];  // row[W+2]=src[W-2], row[W+3]=src[W-3]
    }
    __syncthreads();
    const float* fp = filt + (size_t)g * KK * HW + y * W + t;
    float acc = 0.f;
#pragma unroll
    for (int k = 0; k < KK; k++) acc += row[t + k] * fp[(size_t)k * HW];
    out1[(((size_t)n * C + c) * H + y) * W + t] = acc;

    __shared__ float red[256];
    red[t] = acc * acc;
    __syncthreads();
    for (int off = 128; off; off >>= 1) {
        if (t < off) red[t] += red[t + off];
        __syncthreads();
    }
    if (t == 0) part[bid] = red[0];
}

// ---------------- vertical strip conv + final affine ----------------
// block: 256 threads = x; handles TY=16 rows of one (n,c) plane via register window
#define TY 16
__global__ __launch_bounds__(256) void convv_kernel(const float* __restrict__ out1,
                                                    const float* __restrict__ filt,
                                                    const float* __restrict__ x,
                                                    const float* __restrict__ gamma,
                                                    const float* __restrict__ beta,
                                                    float* __restrict__ out) {
    int bid = blockIdx.x;
    int yt = bid & (H / TY - 1);
    int c = (bid >> 4) & (C - 1);
    int n = bid >> 10;
    int g = c >> 5;
    int t = threadIdx.x;
    int y0 = yt * TY;
    const float* plane = out1 + ((size_t)n * C + c) * HW;
    float win[KK];
#pragma unroll
    for (int i = 0; i < 4; i++) {
        int yy = y0 - 2 + i;
        yy = yy < 0 ? -yy : yy;  // y0-2..y0+1, only low reflection possible here
        win[i] = plane[(size_t)yy * W + t];
    }
    float gm = gamma[c], bt = beta[c];
    for (int dy = 0; dy < TY; dy++) {
        int y = y0 + dy;
        int yy = y + 2;
        yy = (yy >= H) ? (2 * H - 2 - yy) : yy;
        win[4] = plane[(size_t)yy * W + t];
        const float* fp = filt + (size_t)g * KK * HW + (size_t)y * W + t;
        float acc = 0.f;
#pragma unroll
        for (int k = 0; k < KK; k++) acc += win[k] * fp[(size_t)k * HW];
        size_t idx = (((size_t)n * C + c) * H + y) * W + t;
        out[idx] = gm * acc + bt * x[idx];
#pragma unroll
        for (int k = 0; k < 4; k++) win[k] = win[k + 1];
    }
}

extern "C" void kernel_launch(void* const* d_in, const int* in_sizes, int n_in,
                              void* d_out, int out_size, void* d_ws, size_t ws_size,
                              hipStream_t stream) {
    const float* x      = (const float*)d_in[0];
    const float* conv_h = (const float*)d_in[1];
    const float* conv_w = (const float*)d_in[2];
    const float* rv_h   = (const float*)d_in[3];
    const float* rv_w   = (const float*)d_in[4];
    const float* gamma  = (const float*)d_in[5];
    const float* beta   = (const float*)d_in[6];
    float* out = (float*)d_out;

    char* w = (char*)d_ws;
    size_t off = 0;
    float* out1  = (float*)(w + off); off += (size_t)NB * C * HW * 4;   // 67,108,864
    float* xT    = (float*)(w + off); off += (size_t)HW * C * 4;        // 16,777,216
    float* filt  = (float*)(w + off); off += (size_t)NH * HW * 4;       //  2,621,440
    int*   dec   = (int*)  (w + off); off += (size_t)HW * 4;            //    262,144
    int*   order = (int*)  (w + off); off += (size_t)HW * 4;            //    262,144
    int*   hist  = (int*)  (w + off); off += (size_t)NCHUNK * NBINS * 4;//  1,048,576
    int*   boff  = (int*)  (w + off); off += 4096;
    float* part1 = (float*)(w + off); off += (size_t)NB * 256 * 4;      //      4,096
    float* part2 = (float*)(w + off); off += (size_t)NB * C * H * 4;    //    262,144
    int*   best  = (int*)  (w + off); off += 256;

    // ---------------- pass 1: horizontal ----------------
    sumsq_kernel<<<NB * 256, 256, 0, stream>>>(x, part1);
    reduce_argmax_kernel<<<1, 1024, 0, stream>>>(part1, 256, best);
    hash_kernel<<<NCHUNK, 256, 0, stream>>>(x, best, rv_h, xT, dec, hist);
    scan_kernel<<<1, 1024, 0, stream>>>(hist, boff);
    scatter_kernel<<<NCHUNK, 256, 0, stream>>>(dec, hist, boff, order);
    filt_kernel<<<HW / 256, 256, 0, stream>>>(xT, order, conv_h, filt);
    convh_kernel<<<NB * C * H, 256, 0, stream>>>(x, filt, out1, part2);

    // ---------------- pass 2: vertical + affine ----------------
    reduce_argmax_kernel<<<1, 1024, 0, stream>>>(part2, C * H, best);
    hash_kernel<<<NCHUNK, 256, 0, stream>>>(out1, best, rv_w, xT, dec, hist);
    scan_kernel<<<1, 1024, 0, stream>>>(hist, boff);
    scatter_kernel<<<NCHUNK, 256, 0, stream>>>(dec, hist, boff, order);
    filt_kernel<<<HW / 256, 256, 0, stream>>>(xT, order, conv_w, filt);
    convv_kernel<<<NB * C * (H / TY), 256, 0, stream>>>(out1, filt, x, gamma, beta, out);
}

// Round 2
// 211.813 us; speedup vs baseline: 1.1541x; 1.1541x over previous
//
#include <hip/hip_runtime.h>

#define NB 4
#define C 64
#define H 256
#define W 256
#define HW (H * W)
#define NH 10
#define KK 5
#define NBINS 1024
#define CHUNK 256
#define NCHUNK (HW / CHUNK)

// ---------------- per-batch sum of squares (partials per block) ----------------
__global__ __launch_bounds__(256) void sumsq_kernel(const float* __restrict__ x,
                                                    float* __restrict__ part) {
    int bid = blockIdx.x;
    int b = bid >> 8, ch = bid & 255;
    const float4* p = reinterpret_cast<const float4*>(x + (size_t)b * C * HW) + (size_t)ch * 4096;
    float s = 0.f;
    for (int i = threadIdx.x; i < 4096; i += 256) {
        float4 v = p[i];
        s += v.x * v.x + v.y * v.y + v.z * v.z + v.w * v.w;
    }
    __shared__ float red[256];
    red[threadIdx.x] = s;
    __syncthreads();
    for (int off = 128; off; off >>= 1) {
        if (threadIdx.x < off) red[threadIdx.x] += red[threadIdx.x + off];
        __syncthreads();
    }
    if (threadIdx.x == 0) part[bid] = red[0];
}

// ---------------- reduce partials per batch + argmax -> best ----------------
__global__ __launch_bounds__(1024) void reduce_argmax_kernel(const float* __restrict__ part,
                                                             int per_batch,
                                                             int* __restrict__ best) {
    __shared__ float sm[1024];
    float norms[NB];
    int t = threadIdx.x;
    for (int b = 0; b < NB; b++) {
        float s = 0.f;
        for (int i = t; i < per_batch; i += 1024) s += part[(size_t)b * per_batch + i];
        sm[t] = s;
        __syncthreads();
        for (int off = 512; off; off >>= 1) {
            if (t < off) sm[t] += sm[t + off];
            __syncthreads();
        }
        norms[b] = sm[0];
        __syncthreads();
    }
    if (t == 0) {
        int bb = 0;
        float m = norms[0];
        for (int i = 1; i < NB; i++)
            if (norms[i] > m) { m = norms[i]; bb = i; }
        *best = bb;
    }
}

// ---------------- LSH codes + transpose of best plane + per-chunk histogram ----------------
__global__ __launch_bounds__(256) void hash_kernel(const float* __restrict__ Xall,
                                                   const int* __restrict__ bestp,
                                                   const float* __restrict__ rvecs,
                                                   float* __restrict__ xT,
                                                   int* __restrict__ dec,
                                                   int* __restrict__ hist) {
    __shared__ float tile[CHUNK][33];
    __shared__ float rv[NH * C];
    __shared__ int lhist[NBINS];
    int t = threadIdx.x;
    for (int i = t; i < NH * C; i += 256) rv[i] = rvecs[i];
    for (int i = t; i < NBINS; i += 256) lhist[i] = 0;
    int best = *bestp;
    const float* X = Xall + (size_t)best * C * HW;
    int p0 = blockIdx.x * CHUNK;
    float acc[NH];
#pragma unroll
    for (int h2 = 0; h2 < NH; h2++) acc[h2] = 0.f;

    for (int half = 0; half < 2; half++) {
        __syncthreads();
        for (int c = 0; c < 32; c++) tile[t][c] = X[(size_t)(half * 32 + c) * HW + p0 + t];
        __syncthreads();
        float* xrow = xT + (size_t)(p0 + t) * C + half * 32;
        for (int c = 0; c < 32; c += 4) {
            float4 v = make_float4(tile[t][c], tile[t][c + 1], tile[t][c + 2], tile[t][c + 3]);
            *reinterpret_cast<float4*>(xrow + c) = v;
#pragma unroll
            for (int h2 = 0; h2 < NH; h2++) {
                const float* r = rv + h2 * C + half * 32 + c;
                acc[h2] += v.x * r[0] + v.y * r[1] + v.z * r[2] + v.w * r[3];
            }
        }
    }
    int d = 0;
#pragma unroll
    for (int h2 = 0; h2 < NH; h2++) d |= (acc[h2] > 0.f) ? (1 << h2) : 0;
    dec[p0 + t] = d;
    atomicAdd(&lhist[d], 1);
    __syncthreads();
    for (int i = t; i < NBINS; i += 256) hist[(size_t)blockIdx.x * NBINS + i] = lhist[i];
}

// ---------------- per-bin chunk prefix + global bin offsets ----------------
__global__ __launch_bounds__(1024) void scan_kernel(int* __restrict__ hist,
                                                    int* __restrict__ binoff) {
    int b = threadIdx.x;
    int run = 0;
    for (int ch = 0; ch < NCHUNK; ch++) {
        int v = hist[(size_t)ch * NBINS + b];
        hist[(size_t)ch * NBINS + b] = run;
        run += v;
    }
    __shared__ int tot[NBINS];
    tot[b] = run;
    __syncthreads();
    for (int off = 1; off < NBINS; off <<= 1) {
        int v = (b >= off) ? tot[b - off] : 0;
        __syncthreads();
        tot[b] += v;
        __syncthreads();
    }
    binoff[b] = tot[b] - run;
}

// ---------------- stable scatter ----------------
__global__ __launch_bounds__(256) void scatter_kernel(const int* __restrict__ dec,
                                                      const int* __restrict__ hist,
                                                      const int* __restrict__ binoff,
                                                      int* __restrict__ order) {
    __shared__ int keys[CHUNK];
    int p0 = blockIdx.x * CHUNK;
    int t = threadIdx.x;
    int k = dec[p0 + t];
    keys[t] = k;
    __syncthreads();
    int r = 0;
    for (int j = 0; j < t; j++) r += (keys[j] == k) ? 1 : 0;
    int dst = binoff[k] + hist[(size_t)blockIdx.x * NBINS + k] + r;
    order[dst] = p0 + t;
}

// ---------------- filter: sigmoid(conv_w @ bg) ----------------
__global__ __launch_bounds__(256) void filt_kernel(const float* __restrict__ xT,
                                                   const int* __restrict__ order,
                                                   const float* __restrict__ cwg,
                                                   float* __restrict__ filt) {
    __shared__ float cw[NH * C];
    int t = threadIdx.x;
    for (int i = t; i < NH * C; i += 256) cw[i] = cwg[i];
    __syncthreads();
    int p = blockIdx.x * 256 + t;
    int orig = order[p];
    const float4* row = reinterpret_cast<const float4*>(xT + (size_t)orig * C);
    float acc[NH];
#pragma unroll
    for (int h2 = 0; h2 < NH; h2++) acc[h2] = 0.f;
#pragma unroll
    for (int q = 0; q < 16; q++) {
        float4 v = row[q];
#pragma unroll
        for (int h2 = 0; h2 < NH; h2++) {
            const float* r = cw + h2 * C + q * 4;
            acc[h2] += v.x * r[0] + v.y * r[1] + v.z * r[2] + v.w * r[3];
        }
    }
#pragma unroll
    for (int h2 = 0; h2 < NH; h2++) filt[(size_t)h2 * HW + p] = 1.f / (1.f + expf(-acc[h2]));
}

// ---------------- horizontal strip conv (float4) + sumsq partials ----------------
// grid = NB*C*(H/4) blocks; 256 threads; thread: x4=(t&63)*4, row r4=t>>3? -> t>>6
__global__ __launch_bounds__(256) void convh_kernel(const float* __restrict__ X,
                                                    const float* __restrict__ filt,
                                                    float* __restrict__ out1,
                                                    float* __restrict__ part) {
    int bid = blockIdx.x;
    int rb = bid & 63;            // group of 4 rows
    int c = (bid >> 6) & (C - 1);
    int n = bid >> 12;
    int g = c >> 5;
    int t = threadIdx.x;
    int x4 = (t & 63) * 4;
    int y = rb * 4 + (t >> 6);

    const float* src = X + (((size_t)n * C + c) * H + y) * W;
    float4 M = *reinterpret_cast<const float4*>(src + x4);
    float s0, s1, s6, s7;
    if (x4 > 0) {
        float4 L = *reinterpret_cast<const float4*>(src + x4 - 4);
        s0 = L.z; s1 = L.w;
    } else {
        s0 = M.z; s1 = M.y;  // reflect: -2 -> 2, -1 -> 1
    }
    if (x4 < W - 4) {
        float4 R = *reinterpret_cast<const float4*>(src + x4 + 4);
        s6 = R.x; s7 = R.y;
    } else {
        s6 = M.z; s7 = M.y;  // reflect: 256 -> 254, 257 -> 253
    }
    float s[8] = {s0, s1, M.x, M.y, M.z, M.w, s6, s7};

    const float* fb = filt + (size_t)g * KK * HW + (size_t)y * W + x4;
    float4 acc = make_float4(0.f, 0.f, 0.f, 0.f);
#pragma unroll
    for (int k = 0; k < KK; k++) {
        float4 f = *reinterpret_cast<const float4*>(fb + (size_t)k * HW);
        acc.x += s[k] * f.x;
        acc.y += s[k + 1] * f.y;
        acc.z += s[k + 2] * f.z;
        acc.w += s[k + 3] * f.w;
    }
    *reinterpret_cast<float4*>(out1 + (((size_t)n * C + c) * H + y) * W + x4) = acc;

    // per-block sumsq partial (wave shuffle, cheap)
    float ss = acc.x * acc.x + acc.y * acc.y + acc.z * acc.z + acc.w * acc.w;
#pragma unroll
    for (int off = 32; off; off >>= 1) ss += __shfl_down(ss, off);
    __shared__ float wred[4];
    if ((t & 63) == 0) wred[t >> 6] = ss;
    __syncthreads();
    if (t == 0) part[bid] = wred[0] + wred[1] + wred[2] + wred[3];
}

// ---------------- vertical strip conv (float4 sliding window) + affine ----------------
// grid = NB*C*(H/64); 256 threads: x4=(t&63)*4, ysub=t>>6 handles 16 rows
__global__ __launch_bounds__(256) void convv_kernel(const float* __restrict__ out1,
                                                    const float* __restrict__ filt,
                                                    const float* __restrict__ x,
                                                    const float* __restrict__ gamma,
                                                    const float* __restrict__ beta,
                                                    float* __restrict__ out) {
    int bid = blockIdx.x;
    int yc = bid & 3;
    int c = (bid >> 2) & (C - 1);
    int n = bid >> 8;
    int g = c >> 5;
    int t = threadIdx.x;
    int x4 = (t & 63) * 4;
    int ys = yc * 64 + (t >> 6) * 16;

    const float* plane = out1 + ((size_t)n * C + c) * HW;
    float4 win[KK];
#pragma unroll
    for (int i = 0; i < 4; i++) {
        int yy = ys - 2 + i;
        yy = yy < 0 ? -yy : yy;
        win[i] = *reinterpret_cast<const float4*>(plane + (size_t)yy * W + x4);
    }
    float gm = gamma[c], bt = beta[c];
    const float* fgb = filt + (size_t)g * KK * HW;
    for (int dy = 0; dy < 16; dy++) {
        int y = ys + dy;
        int yy = y + 2;
        yy = (yy >= H) ? (2 * H - 2 - yy) : yy;
        win[4] = *reinterpret_cast<const float4*>(plane + (size_t)yy * W + x4);
        const float* fb = fgb + (size_t)y * W + x4;
        float4 acc = make_float4(0.f, 0.f, 0.f, 0.f);
#pragma unroll
        for (int k = 0; k < KK; k++) {
            float4 f = *reinterpret_cast<const float4*>(fb + (size_t)k * HW);
            acc.x += win[k].x * f.x;
            acc.y += win[k].y * f.y;
            acc.z += win[k].z * f.z;
            acc.w += win[k].w * f.w;
        }
        size_t idx = (((size_t)n * C + c) * H + y) * W + x4;
        float4 xv = *reinterpret_cast<const float4*>(x + idx);
        float4 o;
        o.x = gm * acc.x + bt * xv.x;
        o.y = gm * acc.y + bt * xv.y;
        o.z = gm * acc.z + bt * xv.z;
        o.w = gm * acc.w + bt * xv.w;
        *reinterpret_cast<float4*>(out + idx) = o;
#pragma unroll
        for (int k = 0; k < 4; k++) win[k] = win[k + 1];
    }
}

extern "C" void kernel_launch(void* const* d_in, const int* in_sizes, int n_in,
                              void* d_out, int out_size, void* d_ws, size_t ws_size,
                              hipStream_t stream) {
    const float* x      = (const float*)d_in[0];
    const float* conv_h = (const float*)d_in[1];
    const float* conv_w = (const float*)d_in[2];
    const float* rv_h   = (const float*)d_in[3];
    const float* rv_w   = (const float*)d_in[4];
    const float* gamma  = (const float*)d_in[5];
    const float* beta   = (const float*)d_in[6];
    float* out = (float*)d_out;

    char* w = (char*)d_ws;
    size_t off = 0;
    float* out1  = (float*)(w + off); off += (size_t)NB * C * HW * 4;
    float* xT    = (float*)(w + off); off += (size_t)HW * C * 4;
    float* filt  = (float*)(w + off); off += (size_t)NH * HW * 4;
    int*   dec   = (int*)  (w + off); off += (size_t)HW * 4;
    int*   order = (int*)  (w + off); off += (size_t)HW * 4;
    int*   hist  = (int*)  (w + off); off += (size_t)NCHUNK * NBINS * 4;
    int*   boff  = (int*)  (w + off); off += 4096;
    float* part1 = (float*)(w + off); off += (size_t)NB * 256 * 4;
    float* part2 = (float*)(w + off); off += (size_t)NB * 4096 * 4;
    int*   best  = (int*)  (w + off); off += 256;

    // ---------------- pass 1: horizontal ----------------
    sumsq_kernel<<<NB * 256, 256, 0, stream>>>(x, part1);
    reduce_argmax_kernel<<<1, 1024, 0, stream>>>(part1, 256, best);
    hash_kernel<<<NCHUNK, 256, 0, stream>>>(x, best, rv_h, xT, dec, hist);
    scan_kernel<<<1, 1024, 0, stream>>>(hist, boff);
    scatter_kernel<<<NCHUNK, 256, 0, stream>>>(dec, hist, boff, order);
    filt_kernel<<<HW / 256, 256, 0, stream>>>(xT, order, conv_h, filt);
    convh_kernel<<<NB * C * (H / 4), 256, 0, stream>>>(x, filt, out1, part2);

    // ---------------- pass 2: vertical + affine ----------------
    reduce_argmax_kernel<<<1, 1024, 0, stream>>>(part2, 4096, best);
    hash_kernel<<<NCHUNK, 256, 0, stream>>>(out1, best, rv_w, xT, dec, hist);
    scan_kernel<<<1, 1024, 0, stream>>>(hist, boff);
    scatter_kernel<<<NCHUNK, 256, 0, stream>>>(dec, hist, boff, order);
    filt_kernel<<<HW / 256, 256, 0, stream>>>(xT, order, conv_w, filt);
    convv_kernel<<<NB * C * (H / 64), 256, 0, stream>>>(out1, filt, x, gamma, beta, out);
}

// Round 3
// 174.827 us; speedup vs baseline: 1.3983x; 1.2116x over previous
//
#include <hip/hip_runtime.h>

#define NB 4
#define C 64
#define H 256
#define W 256
#define HW (H * W)
#define NH 10
#define KK 5
#define NBINS 1024
#define CHUNK 256
#define NCHUNK (HW / CHUNK)

// ---------------- per-batch sum of squares (partials per block) ----------------
__global__ __launch_bounds__(256) void sumsq_kernel(const float* __restrict__ x,
                                                    float* __restrict__ part) {
    int bid = blockIdx.x;
    int b = bid >> 8, ch = bid & 255;
    const float4* p = reinterpret_cast<const float4*>(x + (size_t)b * C * HW) + (size_t)ch * 4096;
    float s = 0.f;
    for (int i = threadIdx.x; i < 4096; i += 256) {
        float4 v = p[i];
        s += v.x * v.x + v.y * v.y + v.z * v.z + v.w * v.w;
    }
    __shared__ float red[256];
    red[threadIdx.x] = s;
    __syncthreads();
    for (int off = 128; off; off >>= 1) {
        if (threadIdx.x < off) red[threadIdx.x] += red[threadIdx.x + off];
        __syncthreads();
    }
    if (threadIdx.x == 0) part[bid] = red[0];
}

// ---------------- reduce partials per batch + argmax -> best ----------------
__global__ __launch_bounds__(1024) void reduce_argmax_kernel(const float* __restrict__ part,
                                                             int per_batch,
                                                             int* __restrict__ best) {
    __shared__ float sm[1024];
    float norms[NB];
    int t = threadIdx.x;
    for (int b = 0; b < NB; b++) {
        float s = 0.f;
        for (int i = t; i < per_batch; i += 1024) s += part[(size_t)b * per_batch + i];
        sm[t] = s;
        __syncthreads();
        for (int off = 512; off; off >>= 1) {
            if (t < off) sm[t] += sm[t + off];
            __syncthreads();
        }
        norms[b] = sm[0];
        __syncthreads();
    }
    if (t == 0) {
        int bb = 0;
        float m = norms[0];
        for (int i = 1; i < NB; i++)
            if (norms[i] > m) { m = norms[i]; bb = i; }
        *best = bb;
    }
}

// ---------------- LSH codes + transpose of best plane + per-chunk histogram ----------------
// hist written BIN-MAJOR: hist[bin * NCHUNK + chunk]
__global__ __launch_bounds__(256) void hash_kernel(const float* __restrict__ Xall,
                                                   const int* __restrict__ bestp,
                                                   const float* __restrict__ rvecs,
                                                   float* __restrict__ xT,
                                                   int* __restrict__ dec,
                                                   int* __restrict__ hist) {
    __shared__ float tile[CHUNK][33];
    __shared__ float rv[NH * C];
    __shared__ int lhist[NBINS];
    int t = threadIdx.x;
    for (int i = t; i < NH * C; i += 256) rv[i] = rvecs[i];
    for (int i = t; i < NBINS; i += 256) lhist[i] = 0;
    int best = *bestp;
    const float* X = Xall + (size_t)best * C * HW;
    int p0 = blockIdx.x * CHUNK;
    float acc[NH];
#pragma unroll
    for (int h2 = 0; h2 < NH; h2++) acc[h2] = 0.f;

    for (int half = 0; half < 2; half++) {
        __syncthreads();
        for (int c = 0; c < 32; c++) tile[t][c] = X[(size_t)(half * 32 + c) * HW + p0 + t];
        __syncthreads();
        float* xrow = xT + (size_t)(p0 + t) * C + half * 32;
        for (int c = 0; c < 32; c += 4) {
            float4 v = make_float4(tile[t][c], tile[t][c + 1], tile[t][c + 2], tile[t][c + 3]);
            *reinterpret_cast<float4*>(xrow + c) = v;
#pragma unroll
            for (int h2 = 0; h2 < NH; h2++) {
                const float* r = rv + h2 * C + half * 32 + c;
                acc[h2] += v.x * r[0] + v.y * r[1] + v.z * r[2] + v.w * r[3];
            }
        }
    }
    int d = 0;
#pragma unroll
    for (int h2 = 0; h2 < NH; h2++) d |= (acc[h2] > 0.f) ? (1 << h2) : 0;
    dec[p0 + t] = d;
    atomicAdd(&lhist[d], 1);
    __syncthreads();
    for (int i = t; i < NBINS; i += 256) hist[(size_t)i * NCHUNK + blockIdx.x] = lhist[i];
}

// ---------------- parallel per-bin chunk scan: one bin per wave ----------------
// grid = NBINS/4 blocks x 256 threads (4 waves). In-place exclusive prefix over
// the 256 chunk counts of each bin; bin total -> bintot.
__global__ __launch_bounds__(256) void scan1_kernel(int* __restrict__ hist,
                                                    int* __restrict__ bintot) {
    int t = threadIdx.x;
    int lane = t & 63;
    int b = blockIdx.x * 4 + (t >> 6);
    int4 v = *reinterpret_cast<int4*>(hist + (size_t)b * NCHUNK + lane * 4);
    int s0 = v.x;
    int s1 = s0 + v.y;
    int s2 = s1 + v.z;
    int s3 = s2 + v.w;  // inclusive within lane
    int s = s3;
#pragma unroll
    for (int off = 1; off < 64; off <<= 1) {
        int nbr = __shfl_up(s, off);
        if (lane >= off) s += nbr;
    }
    int excl = s - s3;  // exclusive prefix entering this lane
    int4 o;
    o.x = excl;
    o.y = excl + s0;
    o.z = excl + s1;
    o.w = excl + s2;
    *reinterpret_cast<int4*>(hist + (size_t)b * NCHUNK + lane * 4) = o;
    if (lane == 63) bintot[b] = s;
}

// ---------------- exclusive scan over 1024 bin totals ----------------
__global__ __launch_bounds__(1024) void binoff_kernel(const int* __restrict__ bintot,
                                                      int* __restrict__ binoff) {
    __shared__ int tot[NBINS];
    int b = threadIdx.x;
    int own = bintot[b];
    tot[b] = own;
    __syncthreads();
    for (int off = 1; off < NBINS; off <<= 1) {
        int v = (b >= off) ? tot[b - off] : 0;
        __syncthreads();
        tot[b] += v;
        __syncthreads();
    }
    binoff[b] = tot[b] - own;
}

// ---------------- stable scatter ----------------
__global__ __launch_bounds__(256) void scatter_kernel(const int* __restrict__ dec,
                                                      const int* __restrict__ hist,
                                                      const int* __restrict__ binoff,
                                                      int* __restrict__ order) {
    __shared__ int keys[CHUNK];
    int p0 = blockIdx.x * CHUNK;
    int t = threadIdx.x;
    int k = dec[p0 + t];
    keys[t] = k;
    __syncthreads();
    int r = 0;
    for (int j = 0; j < t; j++) r += (keys[j] == k) ? 1 : 0;
    int dst = binoff[k] + hist[(size_t)k * NCHUNK + blockIdx.x] + r;
    order[dst] = p0 + t;
}

// ---------------- filter: sigmoid(conv_w @ bg) ----------------
__global__ __launch_bounds__(256) void filt_kernel(const float* __restrict__ xT,
                                                   const int* __restrict__ order,
                                                   const float* __restrict__ cwg,
                                                   float* __restrict__ filt) {
    __shared__ float cw[NH * C];
    int t = threadIdx.x;
    for (int i = t; i < NH * C; i += 256) cw[i] = cwg[i];
    __syncthreads();
    int p = blockIdx.x * 256 + t;
    int orig = order[p];
    const float4* row = reinterpret_cast<const float4*>(xT + (size_t)orig * C);
    float acc[NH];
#pragma unroll
    for (int h2 = 0; h2 < NH; h2++) acc[h2] = 0.f;
#pragma unroll
    for (int q = 0; q < 16; q++) {
        float4 v = row[q];
#pragma unroll
        for (int h2 = 0; h2 < NH; h2++) {
            const float* r = cw + h2 * C + q * 4;
            acc[h2] += v.x * r[0] + v.y * r[1] + v.z * r[2] + v.w * r[3];
        }
    }
#pragma unroll
    for (int h2 = 0; h2 < NH; h2++) filt[(size_t)h2 * HW + p] = 1.f / (1.f + expf(-acc[h2]));
}

// ---------------- horizontal strip conv (float4) + sumsq partials ----------------
__global__ __launch_bounds__(256) void convh_kernel(const float* __restrict__ X,
                                                    const float* __restrict__ filt,
                                                    float* __restrict__ out1,
                                                    float* __restrict__ part) {
    int bid = blockIdx.x;
    int rb = bid & 63;
    int c = (bid >> 6) & (C - 1);
    int n = bid >> 12;
    int g = c >> 5;
    int t = threadIdx.x;
    int x4 = (t & 63) * 4;
    int y = rb * 4 + (t >> 6);

    const float* src = X + (((size_t)n * C + c) * H + y) * W;
    float4 M = *reinterpret_cast<const float4*>(src + x4);
    float s0, s1, s6, s7;
    if (x4 > 0) {
        float4 L = *reinterpret_cast<const float4*>(src + x4 - 4);
        s0 = L.z; s1 = L.w;
    } else {
        s0 = M.z; s1 = M.y;
    }
    if (x4 < W - 4) {
        float4 R = *reinterpret_cast<const float4*>(src + x4 + 4);
        s6 = R.x; s7 = R.y;
    } else {
        s6 = M.z; s7 = M.y;
    }
    float s[8] = {s0, s1, M.x, M.y, M.z, M.w, s6, s7};

    const float* fb = filt + (size_t)g * KK * HW + (size_t)y * W + x4;
    float4 acc = make_float4(0.f, 0.f, 0.f, 0.f);
#pragma unroll
    for (int k = 0; k < KK; k++) {
        float4 f = *reinterpret_cast<const float4*>(fb + (size_t)k * HW);
        acc.x += s[k] * f.x;
        acc.y += s[k + 1] * f.y;
        acc.z += s[k + 2] * f.z;
        acc.w += s[k + 3] * f.w;
    }
    *reinterpret_cast<float4*>(out1 + (((size_t)n * C + c) * H + y) * W + x4) = acc;

    float ss = acc.x * acc.x + acc.y * acc.y + acc.z * acc.z + acc.w * acc.w;
#pragma unroll
    for (int off = 32; off; off >>= 1) ss += __shfl_down(ss, off);
    __shared__ float wred[4];
    if ((t & 63) == 0) wred[t >> 6] = ss;
    __syncthreads();
    if (t == 0) part[bid] = wred[0] + wred[1] + wred[2] + wred[3];
}

// ---------------- vertical strip conv (float4 sliding window) + affine ----------------
__global__ __launch_bounds__(256) void convv_kernel(const float* __restrict__ out1,
                                                    const float* __restrict__ filt,
                                                    const float* __restrict__ x,
                                                    const float* __restrict__ gamma,
                                                    const float* __restrict__ beta,
                                                    float* __restrict__ out) {
    int bid = blockIdx.x;
    int yc = bid & 3;
    int c = (bid >> 2) & (C - 1);
    int n = bid >> 8;
    int g = c >> 5;
    int t = threadIdx.x;
    int x4 = (t & 63) * 4;
    int ys = yc * 64 + (t >> 6) * 16;

    const float* plane = out1 + ((size_t)n * C + c) * HW;
    float4 win[KK];
#pragma unroll
    for (int i = 0; i < 4; i++) {
        int yy = ys - 2 + i;
        yy = yy < 0 ? -yy : yy;
        win[i] = *reinterpret_cast<const float4*>(plane + (size_t)yy * W + x4);
    }
    float gm = gamma[c], bt = beta[c];
    const float* fgb = filt + (size_t)g * KK * HW;
    for (int dy = 0; dy < 16; dy++) {
        int y = ys + dy;
        int yy = y + 2;
        yy = (yy >= H) ? (2 * H - 2 - yy) : yy;
        win[4] = *reinterpret_cast<const float4*>(plane + (size_t)yy * W + x4);
        const float* fb = fgb + (size_t)y * W + x4;
        float4 acc = make_float4(0.f, 0.f, 0.f, 0.f);
#pragma unroll
        for (int k = 0; k < KK; k++) {
            float4 f = *reinterpret_cast<const float4*>(fb + (size_t)k * HW);
            acc.x += win[k].x * f.x;
            acc.y += win[k].y * f.y;
            acc.z += win[k].z * f.z;
            acc.w += win[k].w * f.w;
        }
        size_t idx = (((size_t)n * C + c) * H + y) * W + x4;
        float4 xv = *reinterpret_cast<const float4*>(x + idx);
        float4 o;
        o.x = gm * acc.x + bt * xv.x;
        o.y = gm * acc.y + bt * xv.y;
        o.z = gm * acc.z + bt * xv.z;
        o.w = gm * acc.w + bt * xv.w;
        *reinterpret_cast<float4*>(out + idx) = o;
#pragma unroll
        for (int k = 0; k < 4; k++) win[k] = win[k + 1];
    }
}

extern "C" void kernel_launch(void* const* d_in, const int* in_sizes, int n_in,
                              void* d_out, int out_size, void* d_ws, size_t ws_size,
                              hipStream_t stream) {
    const float* x      = (const float*)d_in[0];
    const float* conv_h = (const float*)d_in[1];
    const float* conv_w = (const float*)d_in[2];
    const float* rv_h   = (const float*)d_in[3];
    const float* rv_w   = (const float*)d_in[4];
    const float* gamma  = (const float*)d_in[5];
    const float* beta   = (const float*)d_in[6];
    float* out = (float*)d_out;

    char* w = (char*)d_ws;
    size_t off = 0;
    float* out1   = (float*)(w + off); off += (size_t)NB * C * HW * 4;
    float* xT     = (float*)(w + off); off += (size_t)HW * C * 4;
    float* filt   = (float*)(w + off); off += (size_t)NH * HW * 4;
    int*   dec    = (int*)  (w + off); off += (size_t)HW * 4;
    int*   order  = (int*)  (w + off); off += (size_t)HW * 4;
    int*   hist   = (int*)  (w + off); off += (size_t)NCHUNK * NBINS * 4;
    int*   bintot = (int*)  (w + off); off += 4096;
    int*   boff   = (int*)  (w + off); off += 4096;
    float* part1  = (float*)(w + off); off += (size_t)NB * 256 * 4;
    float* part2  = (float*)(w + off); off += (size_t)NB * 4096 * 4;
    int*   best   = (int*)  (w + off); off += 256;

    // ---------------- pass 1: horizontal ----------------
    sumsq_kernel<<<NB * 256, 256, 0, stream>>>(x, part1);
    reduce_argmax_kernel<<<1, 1024, 0, stream>>>(part1, 256, best);
    hash_kernel<<<NCHUNK, 256, 0, stream>>>(x, best, rv_h, xT, dec, hist);
    scan1_kernel<<<NBINS / 4, 256, 0, stream>>>(hist, bintot);
    binoff_kernel<<<1, 1024, 0, stream>>>(bintot, boff);
    scatter_kernel<<<NCHUNK, 256, 0, stream>>>(dec, hist, boff, order);
    filt_kernel<<<HW / 256, 256, 0, stream>>>(xT, order, conv_h, filt);
    convh_kernel<<<NB * C * (H / 4), 256, 0, stream>>>(x, filt, out1, part2);

    // ---------------- pass 2: vertical + affine ----------------
    reduce_argmax_kernel<<<1, 1024, 0, stream>>>(part2, 4096, best);
    hash_kernel<<<NCHUNK, 256, 0, stream>>>(out1, best, rv_w, xT, dec, hist);
    scan1_kernel<<<NBINS / 4, 256, 0, stream>>>(hist, bintot);
    binoff_kernel<<<1, 1024, 0, stream>>>(bintot, boff);
    scatter_kernel<<<NCHUNK, 256, 0, stream>>>(dec, hist, boff, order);
    filt_kernel<<<HW / 256, 256, 0, stream>>>(xT, order, conv_w, filt);
    convv_kernel<<<NB * C * (H / 64), 256, 0, stream>>>(out1, filt, x, gamma, beta, out);
}

// Round 4
// 161.133 us; speedup vs baseline: 1.5171x; 1.0850x over previous
//
#include <hip/hip_runtime.h>

#define NB 4
#define C 64
#define H 256
#define W 256
#define HW (H * W)
#define NH 10
#define KK 5
#define NBINS 1024
#define CHUNK 256
#define NCHUNK (HW / CHUNK)

// ---------------- per-batch sum of squares (64 partials per batch) ----------------
// grid = NB*64; block bid: batch = bid>>6, chunk = bid&63 (16384 float4 each)
__global__ __launch_bounds__(256) void sumsq_kernel(const float* __restrict__ x,
                                                    float* __restrict__ part) {
    int bid = blockIdx.x;
    int b = bid >> 6, ch = bid & 63;
    const float4* p = reinterpret_cast<const float4*>(x + (size_t)b * C * HW) + (size_t)ch * 16384;
    float s = 0.f;
    for (int i = threadIdx.x; i < 16384; i += 256) {
        float4 v = p[i];
        s += v.x * v.x + v.y * v.y + v.z * v.z + v.w * v.w;
    }
    __shared__ float red[256];
    red[threadIdx.x] = s;
    __syncthreads();
    for (int off = 128; off; off >>= 1) {
        if (threadIdx.x < off) red[threadIdx.x] += red[threadIdx.x + off];
        __syncthreads();
    }
    if (threadIdx.x == 0) part[bid] = red[0];
}

// ---------------- LSH + conv projections of best plane + per-chunk histogram ----------------
// Fused argmax: every block redundantly reduces `part` to find the best batch.
// Outputs: dec[q], filtU[q*12+h] = sigmoid(conv_h[h]·row(q)), hist bin-major.
__global__ __launch_bounds__(256) void hash_kernel(const float* __restrict__ Xall,
                                                   const float* __restrict__ part,
                                                   int per_batch,
                                                   const float* __restrict__ rvecs,
                                                   const float* __restrict__ cwg,
                                                   float* __restrict__ filtU,
                                                   int* __restrict__ dec,
                                                   int* __restrict__ hist) {
    __shared__ float tile[CHUNK][33];
    __shared__ float rv[NH * C];
    __shared__ float cw[NH * C];
    __shared__ int lhist[NBINS];
    __shared__ float4 red4[256];
    int t = threadIdx.x;
    for (int i = t; i < NH * C; i += 256) { rv[i] = rvecs[i]; cw[i] = cwg[i]; }
    for (int i = t; i < NBINS; i += 256) lhist[i] = 0;

    // redundant per-block argmax over batch norms
    float4 ss = make_float4(0.f, 0.f, 0.f, 0.f);
    for (int i = t; i < per_batch; i += 256) {
        ss.x += part[0 * per_batch + i];
        ss.y += part[1 * per_batch + i];
        ss.z += part[2 * per_batch + i];
        ss.w += part[3 * per_batch + i];
    }
    red4[t] = ss;
    __syncthreads();
    for (int off = 128; off; off >>= 1) {
        if (t < off) {
            red4[t].x += red4[t + off].x;
            red4[t].y += red4[t + off].y;
            red4[t].z += red4[t + off].z;
            red4[t].w += red4[t + off].w;
        }
        __syncthreads();
    }
    float4 nm = red4[0];
    float nv[NB] = {nm.x, nm.y, nm.z, nm.w};
    int best = 0;
    float m = nv[0];
#pragma unroll
    for (int i = 1; i < NB; i++)
        if (nv[i] > m) { m = nv[i]; best = i; }

    const float* X = Xall + (size_t)best * C * HW;
    int p0 = blockIdx.x * CHUNK;
    float acc[NH], cacc[NH];
#pragma unroll
    for (int h2 = 0; h2 < NH; h2++) { acc[h2] = 0.f; cacc[h2] = 0.f; }

    for (int half = 0; half < 2; half++) {
        __syncthreads();
        for (int c = 0; c < 32; c++) tile[t][c] = X[(size_t)(half * 32 + c) * HW + p0 + t];
        __syncthreads();
        for (int c = 0; c < 32; c += 4) {
            float4 v = make_float4(tile[t][c], tile[t][c + 1], tile[t][c + 2], tile[t][c + 3]);
#pragma unroll
            for (int h2 = 0; h2 < NH; h2++) {
                const float* r = rv + h2 * C + half * 32 + c;
                const float* cc = cw + h2 * C + half * 32 + c;
                acc[h2] += v.x * r[0] + v.y * r[1] + v.z * r[2] + v.w * r[3];
                cacc[h2] += v.x * cc[0] + v.y * cc[1] + v.z * cc[2] + v.w * cc[3];
            }
        }
    }
    int d = 0;
#pragma unroll
    for (int h2 = 0; h2 < NH; h2++) d |= (acc[h2] > 0.f) ? (1 << h2) : 0;
    dec[p0 + t] = d;
    atomicAdd(&lhist[d], 1);

    float* fu = filtU + (size_t)(p0 + t) * 12;
    float s01 = 1.f / (1.f + expf(-cacc[0])), s1 = 1.f / (1.f + expf(-cacc[1]));
    float s2 = 1.f / (1.f + expf(-cacc[2])), s3 = 1.f / (1.f + expf(-cacc[3]));
    float s4 = 1.f / (1.f + expf(-cacc[4])), s5 = 1.f / (1.f + expf(-cacc[5]));
    float s6 = 1.f / (1.f + expf(-cacc[6])), s7 = 1.f / (1.f + expf(-cacc[7]));
    float s8 = 1.f / (1.f + expf(-cacc[8])), s9 = 1.f / (1.f + expf(-cacc[9]));
    *reinterpret_cast<float4*>(fu + 0) = make_float4(s01, s1, s2, s3);
    *reinterpret_cast<float4*>(fu + 4) = make_float4(s4, s5, s6, s7);
    *reinterpret_cast<float4*>(fu + 8) = make_float4(s8, s9, 0.f, 0.f);

    __syncthreads();
    for (int i = t; i < NBINS; i += 256) hist[(size_t)i * NCHUNK + blockIdx.x] = lhist[i];
}

// ---------------- parallel per-bin chunk scan: one bin per wave ----------------
__global__ __launch_bounds__(256) void scan1_kernel(int* __restrict__ hist,
                                                    int* __restrict__ bintot) {
    int t = threadIdx.x;
    int lane = t & 63;
    int b = blockIdx.x * 4 + (t >> 6);
    int4 v = *reinterpret_cast<int4*>(hist + (size_t)b * NCHUNK + lane * 4);
    int s0 = v.x;
    int s1 = s0 + v.y;
    int s2 = s1 + v.z;
    int s3 = s2 + v.w;
    int s = s3;
#pragma unroll
    for (int off = 1; off < 64; off <<= 1) {
        int nbr = __shfl_up(s, off);
        if (lane >= off) s += nbr;
    }
    int excl = s - s3;
    int4 o;
    o.x = excl;
    o.y = excl + s0;
    o.z = excl + s1;
    o.w = excl + s2;
    *reinterpret_cast<int4*>(hist + (size_t)b * NCHUNK + lane * 4) = o;
    if (lane == 63) bintot[b] = s;
}

// ---------------- stable scatter (binoff fused via LDS scan of bintot) ----------------
__global__ __launch_bounds__(256) void scatter_kernel(const int* __restrict__ dec,
                                                      const int* __restrict__ hist,
                                                      const int* __restrict__ bintot,
                                                      int* __restrict__ order) {
    __shared__ int boffs[NBINS];
    __shared__ int wtot[4];
    __shared__ int keys[CHUNK];
    int t = threadIdx.x;
    int lane = t & 63;
    int w = t >> 6;
    int4 v = *reinterpret_cast<const int4*>(bintot + t * 4);
    int s0 = v.x, s1 = s0 + v.y, s2 = s1 + v.z, s3 = s2 + v.w;
    int s = s3;
#pragma unroll
    for (int off = 1; off < 64; off <<= 1) {
        int nbr = __shfl_up(s, off);
        if (lane >= off) s += nbr;
    }
    int excl = s - s3;
    if (lane == 63) wtot[w] = s;
    __syncthreads();
    int wbase = 0;
#pragma unroll
    for (int i = 0; i < 4; i++) wbase += (i < w) ? wtot[i] : 0;
    boffs[t * 4 + 0] = wbase + excl;
    boffs[t * 4 + 1] = wbase + excl + s0;
    boffs[t * 4 + 2] = wbase + excl + s1;
    boffs[t * 4 + 3] = wbase + excl + s2;

    int p0 = blockIdx.x * CHUNK;
    int k = dec[p0 + t];
    keys[t] = k;
    __syncthreads();
    int r = 0;
    for (int j = 0; j < t; j++) r += (keys[j] == k) ? 1 : 0;
    int dst = boffs[k] + hist[(size_t)k * NCHUNK + blockIdx.x] + r;
    order[dst] = p0 + t;
}

// ---------------- gather sigmoid'd projections into plane-major filt ----------------
__global__ __launch_bounds__(256) void filtsig_kernel(const float* __restrict__ filtU,
                                                      const int* __restrict__ order,
                                                      float* __restrict__ filt) {
    int p = blockIdx.x * 256 + threadIdx.x;
    int orig = order[p];
    const float4* fu = reinterpret_cast<const float4*>(filtU + (size_t)orig * 12);
    float4 a = fu[0], b4 = fu[1], c4 = fu[2];
    float v[10] = {a.x, a.y, a.z, a.w, b4.x, b4.y, b4.z, b4.w, c4.x, c4.y};
#pragma unroll
    for (int h2 = 0; h2 < NH; h2++) filt[(size_t)h2 * HW + p] = v[h2];
}

// ---------------- horizontal strip conv (float4) + sumsq partials ----------------
__global__ __launch_bounds__(256) void convh_kernel(const float* __restrict__ X,
                                                    const float* __restrict__ filt,
                                                    float* __restrict__ out1,
                                                    float* __restrict__ part) {
    int bid = blockIdx.x;
    int rb = bid & 63;
    int c = (bid >> 6) & (C - 1);
    int n = bid >> 12;
    int g = c >> 5;
    int t = threadIdx.x;
    int x4 = (t & 63) * 4;
    int y = rb * 4 + (t >> 6);

    const float* src = X + (((size_t)n * C + c) * H + y) * W;
    float4 M = *reinterpret_cast<const float4*>(src + x4);
    float s0, s1, s6, s7;
    if (x4 > 0) {
        float4 L = *reinterpret_cast<const float4*>(src + x4 - 4);
        s0 = L.z; s1 = L.w;
    } else {
        s0 = M.z; s1 = M.y;
    }
    if (x4 < W - 4) {
        float4 R = *reinterpret_cast<const float4*>(src + x4 + 4);
        s6 = R.x; s7 = R.y;
    } else {
        s6 = M.z; s7 = M.y;
    }
    float s[8] = {s0, s1, M.x, M.y, M.z, M.w, s6, s7};

    const float* fb = filt + (size_t)g * KK * HW + (size_t)y * W + x4;
    float4 acc = make_float4(0.f, 0.f, 0.f, 0.f);
#pragma unroll
    for (int k = 0; k < KK; k++) {
        float4 f = *reinterpret_cast<const float4*>(fb + (size_t)k * HW);
        acc.x += s[k] * f.x;
        acc.y += s[k + 1] * f.y;
        acc.z += s[k + 2] * f.z;
        acc.w += s[k + 3] * f.w;
    }
    *reinterpret_cast<float4*>(out1 + (((size_t)n * C + c) * H + y) * W + x4) = acc;

    float ss = acc.x * acc.x + acc.y * acc.y + acc.z * acc.z + acc.w * acc.w;
#pragma unroll
    for (int off = 32; off; off >>= 1) ss += __shfl_down(ss, off);
    __shared__ float wred[4];
    if ((t & 63) == 0) wred[t >> 6] = ss;
    __syncthreads();
    if (t == 0) part[bid] = wred[0] + wred[1] + wred[2] + wred[3];
}

// ---------------- vertical strip conv (float4 sliding window) + affine ----------------
__global__ __launch_bounds__(256) void convv_kernel(const float* __restrict__ out1,
                                                    const float* __restrict__ filt,
                                                    const float* __restrict__ x,
                                                    const float* __restrict__ gamma,
                                                    const float* __restrict__ beta,
                                                    float* __restrict__ out) {
    int bid = blockIdx.x;
    int yc = bid & 3;
    int c = (bid >> 2) & (C - 1);
    int n = bid >> 8;
    int g = c >> 5;
    int t = threadIdx.x;
    int x4 = (t & 63) * 4;
    int ys = yc * 64 + (t >> 6) * 16;

    const float* plane = out1 + ((size_t)n * C + c) * HW;
    float4 win[KK];
#pragma unroll
    for (int i = 0; i < 4; i++) {
        int yy = ys - 2 + i;
        yy = yy < 0 ? -yy : yy;
        win[i] = *reinterpret_cast<const float4*>(plane + (size_t)yy * W + x4);
    }
    float gm = gamma[c], bt = beta[c];
    const float* fgb = filt + (size_t)g * KK * HW;
    for (int dy = 0; dy < 16; dy++) {
        int y = ys + dy;
        int yy = y + 2;
        yy = (yy >= H) ? (2 * H - 2 - yy) : yy;
        win[4] = *reinterpret_cast<const float4*>(plane + (size_t)yy * W + x4);
        const float* fb = fgb + (size_t)y * W + x4;
        float4 acc = make_float4(0.f, 0.f, 0.f, 0.f);
#pragma unroll
        for (int k = 0; k < KK; k++) {
            float4 f = *reinterpret_cast<const float4*>(fb + (size_t)k * HW);
            acc.x += win[k].x * f.x;
            acc.y += win[k].y * f.y;
            acc.z += win[k].z * f.z;
            acc.w += win[k].w * f.w;
        }
        size_t idx = (((size_t)n * C + c) * H + y) * W + x4;
        float4 xv = *reinterpret_cast<const float4*>(x + idx);
        float4 o;
        o.x = gm * acc.x + bt * xv.x;
        o.y = gm * acc.y + bt * xv.y;
        o.z = gm * acc.z + bt * xv.z;
        o.w = gm * acc.w + bt * xv.w;
        *reinterpret_cast<float4*>(out + idx) = o;
#pragma unroll
        for (int k = 0; k < 4; k++) win[k] = win[k + 1];
    }
}

extern "C" void kernel_launch(void* const* d_in, const int* in_sizes, int n_in,
                              void* d_out, int out_size, void* d_ws, size_t ws_size,
                              hipStream_t stream) {
    const float* x      = (const float*)d_in[0];
    const float* conv_h = (const float*)d_in[1];
    const float* conv_w = (const float*)d_in[2];
    const float* rv_h   = (const float*)d_in[3];
    const float* rv_w   = (const float*)d_in[4];
    const float* gamma  = (const float*)d_in[5];
    const float* beta   = (const float*)d_in[6];
    float* out = (float*)d_out;

    char* w = (char*)d_ws;
    size_t off = 0;
    float* out1   = (float*)(w + off); off += (size_t)NB * C * HW * 4;
    float* filtU  = (float*)(w + off); off += (size_t)HW * 12 * 4;
    float* filt   = (float*)(w + off); off += (size_t)NH * HW * 4;
    int*   dec    = (int*)  (w + off); off += (size_t)HW * 4;
    int*   order  = (int*)  (w + off); off += (size_t)HW * 4;
    int*   hist   = (int*)  (w + off); off += (size_t)NCHUNK * NBINS * 4;
    int*   bintot = (int*)  (w + off); off += 4096;
    float* part1  = (float*)(w + off); off += (size_t)NB * 64 * 4;
    float* part2  = (float*)(w + off); off += (size_t)NB * 4096 * 4;

    // ---------------- pass 1: horizontal ----------------
    sumsq_kernel<<<NB * 64, 256, 0, stream>>>(x, part1);
    hash_kernel<<<NCHUNK, 256, 0, stream>>>(x, part1, 64, rv_h, conv_h, filtU, dec, hist);
    scan1_kernel<<<NBINS / 4, 256, 0, stream>>>(hist, bintot);
    scatter_kernel<<<NCHUNK, 256, 0, stream>>>(dec, hist, bintot, order);
    filtsig_kernel<<<HW / 256, 256, 0, stream>>>(filtU, order, filt);
    convh_kernel<<<NB * C * (H / 4), 256, 0, stream>>>(x, filt, out1, part2);

    // ---------------- pass 2: vertical + affine ----------------
    hash_kernel<<<NCHUNK, 256, 0, stream>>>(out1, part2, 4096, rv_w, conv_w, filtU, dec, hist);
    scan1_kernel<<<NBINS / 4, 256, 0, stream>>>(hist, bintot);
    scatter_kernel<<<NCHUNK, 256, 0, stream>>>(dec, hist, bintot, order);
    filtsig_kernel<<<HW / 256, 256, 0, stream>>>(filtU, order, filt);
    convv_kernel<<<NB * C * (H / 64), 256, 0, stream>>>(out1, filt, x, gamma, beta, out);
}

// Round 5
// 151.465 us; speedup vs baseline: 1.6140x; 1.0638x over previous
//
#include <hip/hip_runtime.h>

#define NB 4
#define C 64
#define H 256
#define W 256
#define HW (H * W)
#define NH 10
#define KK 5
#define NBINS 1024
#define CHUNK 256
#define NCHUNK (HW / CHUNK)

// ---------------- per-batch sum of squares (256 partials per batch) ----------------
// grid = NB*256; block bid: batch = bid>>8, chunk = bid&255 (4096 float4 = 64 KB each)
__global__ __launch_bounds__(256) void sumsq_kernel(const float* __restrict__ x,
                                                    float* __restrict__ part) {
    int bid = blockIdx.x;
    int b = bid >> 8, ch = bid & 255;
    const float4* p = reinterpret_cast<const float4*>(x + (size_t)b * C * HW) + (size_t)ch * 4096;
    float s = 0.f;
    for (int i = threadIdx.x; i < 4096; i += 256) {
        float4 v = p[i];
        s += v.x * v.x + v.y * v.y + v.z * v.z + v.w * v.w;
    }
    __shared__ float red[256];
    red[threadIdx.x] = s;
    __syncthreads();
    for (int off = 128; off; off >>= 1) {
        if (threadIdx.x < off) red[threadIdx.x] += red[threadIdx.x + off];
        __syncthreads();
    }
    if (threadIdx.x == 0) part[bid] = red[0];
}

// ---------------- LSH + conv projections of best plane + per-chunk histogram ----------------
// Fused argmax: every block redundantly reduces `part` to find the best batch.
__global__ __launch_bounds__(256) void hash_kernel(const float* __restrict__ Xall,
                                                   const float* __restrict__ part,
                                                   int per_batch,
                                                   const float* __restrict__ rvecs,
                                                   const float* __restrict__ cwg,
                                                   float* __restrict__ filtU,
                                                   int* __restrict__ dec,
                                                   int* __restrict__ hist) {
    __shared__ float tile[CHUNK][33];
    __shared__ float rv[NH * C];
    __shared__ float cw[NH * C];
    __shared__ int lhist[NBINS];
    __shared__ float4 red4[256];
    int t = threadIdx.x;
    for (int i = t; i < NH * C; i += 256) { rv[i] = rvecs[i]; cw[i] = cwg[i]; }
    for (int i = t; i < NBINS; i += 256) lhist[i] = 0;

    // redundant per-block argmax over batch norms
    float4 ss = make_float4(0.f, 0.f, 0.f, 0.f);
    for (int i = t; i < per_batch; i += 256) {
        ss.x += part[0 * per_batch + i];
        ss.y += part[1 * per_batch + i];
        ss.z += part[2 * per_batch + i];
        ss.w += part[3 * per_batch + i];
    }
    red4[t] = ss;
    __syncthreads();
    for (int off = 128; off; off >>= 1) {
        if (t < off) {
            red4[t].x += red4[t + off].x;
            red4[t].y += red4[t + off].y;
            red4[t].z += red4[t + off].z;
            red4[t].w += red4[t + off].w;
        }
        __syncthreads();
    }
    float4 nm = red4[0];
    float nv[NB] = {nm.x, nm.y, nm.z, nm.w};
    int best = 0;
    float m = nv[0];
#pragma unroll
    for (int i = 1; i < NB; i++)
        if (nv[i] > m) { m = nv[i]; best = i; }

    const float* X = Xall + (size_t)best * C * HW;
    int p0 = blockIdx.x * CHUNK;
    float acc[NH], cacc[NH];
#pragma unroll
    for (int h2 = 0; h2 < NH; h2++) { acc[h2] = 0.f; cacc[h2] = 0.f; }

    for (int half = 0; half < 2; half++) {
        __syncthreads();
        for (int c = 0; c < 32; c++) tile[t][c] = X[(size_t)(half * 32 + c) * HW + p0 + t];
        __syncthreads();
        for (int c = 0; c < 32; c += 4) {
            float4 v = make_float4(tile[t][c], tile[t][c + 1], tile[t][c + 2], tile[t][c + 3]);
#pragma unroll
            for (int h2 = 0; h2 < NH; h2++) {
                const float* r = rv + h2 * C + half * 32 + c;
                const float* cc = cw + h2 * C + half * 32 + c;
                acc[h2] += v.x * r[0] + v.y * r[1] + v.z * r[2] + v.w * r[3];
                cacc[h2] += v.x * cc[0] + v.y * cc[1] + v.z * cc[2] + v.w * cc[3];
            }
        }
    }
    int d = 0;
#pragma unroll
    for (int h2 = 0; h2 < NH; h2++) d |= (acc[h2] > 0.f) ? (1 << h2) : 0;
    dec[p0 + t] = d;
    atomicAdd(&lhist[d], 1);

    float* fu = filtU + (size_t)(p0 + t) * 12;
    float s01 = 1.f / (1.f + expf(-cacc[0])), s1 = 1.f / (1.f + expf(-cacc[1]));
    float s2 = 1.f / (1.f + expf(-cacc[2])), s3 = 1.f / (1.f + expf(-cacc[3]));
    float s4 = 1.f / (1.f + expf(-cacc[4])), s5 = 1.f / (1.f + expf(-cacc[5]));
    float s6 = 1.f / (1.f + expf(-cacc[6])), s7 = 1.f / (1.f + expf(-cacc[7]));
    float s8 = 1.f / (1.f + expf(-cacc[8])), s9 = 1.f / (1.f + expf(-cacc[9]));
    *reinterpret_cast<float4*>(fu + 0) = make_float4(s01, s1, s2, s3);
    *reinterpret_cast<float4*>(fu + 4) = make_float4(s4, s5, s6, s7);
    *reinterpret_cast<float4*>(fu + 8) = make_float4(s8, s9, 0.f, 0.f);

    __syncthreads();
    for (int i = t; i < NBINS; i += 256) hist[(size_t)i * NCHUNK + blockIdx.x] = lhist[i];
}

// ---------------- parallel per-bin chunk scan: one bin per wave ----------------
__global__ __launch_bounds__(256) void scan1_kernel(int* __restrict__ hist,
                                                    int* __restrict__ bintot) {
    int t = threadIdx.x;
    int lane = t & 63;
    int b = blockIdx.x * 4 + (t >> 6);
    int4 v = *reinterpret_cast<int4*>(hist + (size_t)b * NCHUNK + lane * 4);
    int s0 = v.x;
    int s1 = s0 + v.y;
    int s2 = s1 + v.z;
    int s3 = s2 + v.w;
    int s = s3;
#pragma unroll
    for (int off = 1; off < 64; off <<= 1) {
        int nbr = __shfl_up(s, off);
        if (lane >= off) s += nbr;
    }
    int excl = s - s3;
    int4 o;
    o.x = excl;
    o.y = excl + s0;
    o.z = excl + s1;
    o.w = excl + s2;
    *reinterpret_cast<int4*>(hist + (size_t)b * NCHUNK + lane * 4) = o;
    if (lane == 63) bintot[b] = s;
}

// ---------------- stable scatter (binoff fused via LDS scan of bintot) ----------------
__global__ __launch_bounds__(256) void scatter_kernel(const int* __restrict__ dec,
                                                      const int* __restrict__ hist,
                                                      const int* __restrict__ bintot,
                                                      int* __restrict__ order) {
    __shared__ int boffs[NBINS];
    __shared__ int wtot[4];
    __shared__ int keys[CHUNK];
    int t = threadIdx.x;
    int lane = t & 63;
    int w = t >> 6;
    int4 v = *reinterpret_cast<const int4*>(bintot + t * 4);
    int s0 = v.x, s1 = s0 + v.y, s2 = s1 + v.z, s3 = s2 + v.w;
    int s = s3;
#pragma unroll
    for (int off = 1; off < 64; off <<= 1) {
        int nbr = __shfl_up(s, off);
        if (lane >= off) s += nbr;
    }
    int excl = s - s3;
    if (lane == 63) wtot[w] = s;
    __syncthreads();
    int wbase = 0;
#pragma unroll
    for (int i = 0; i < 4; i++) wbase += (i < w) ? wtot[i] : 0;
    boffs[t * 4 + 0] = wbase + excl;
    boffs[t * 4 + 1] = wbase + excl + s0;
    boffs[t * 4 + 2] = wbase + excl + s1;
    boffs[t * 4 + 3] = wbase + excl + s2;

    int p0 = blockIdx.x * CHUNK;
    int k = dec[p0 + t];
    keys[t] = k;
    __syncthreads();
    int r = 0;
    for (int j = 0; j < t; j++) r += (keys[j] == k) ? 1 : 0;
    int dst = boffs[k] + hist[(size_t)k * NCHUNK + blockIdx.x] + r;
    order[dst] = p0 + t;
}

// ---------------- gather sigmoid'd projections into plane-major filt ----------------
__global__ __launch_bounds__(256) void filtsig_kernel(const float* __restrict__ filtU,
                                                      const int* __restrict__ order,
                                                      float* __restrict__ filt) {
    int p = blockIdx.x * 256 + threadIdx.x;
    int orig = order[p];
    const float4* fu = reinterpret_cast<const float4*>(filtU + (size_t)orig * 12);
    float4 a = fu[0], b4 = fu[1], c4 = fu[2];
    float v[10] = {a.x, a.y, a.z, a.w, b4.x, b4.y, b4.z, b4.w, c4.x, c4.y};
#pragma unroll
    for (int h2 = 0; h2 < NH; h2++) filt[(size_t)h2 * HW + p] = v[h2];
}

// ---------------- horizontal strip conv (float4) + sumsq partials ----------------
__global__ __launch_bounds__(256) void convh_kernel(const float* __restrict__ X,
                                                    const float* __restrict__ filt,
                                                    float* __restrict__ out1,
                                                    float* __restrict__ part) {
    int bid = blockIdx.x;
    int rb = bid & 63;
    int c = (bid >> 6) & (C - 1);
    int n = bid >> 12;
    int g = c >> 5;
    int t = threadIdx.x;
    int x4 = (t & 63) * 4;
    int y = rb * 4 + (t >> 6);

    const float* src = X + (((size_t)n * C + c) * H + y) * W;
    float4 M = *reinterpret_cast<const float4*>(src + x4);
    float s0, s1, s6, s7;
    if (x4 > 0) {
        float4 L = *reinterpret_cast<const float4*>(src + x4 - 4);
        s0 = L.z; s1 = L.w;
    } else {
        s0 = M.z; s1 = M.y;
    }
    if (x4 < W - 4) {
        float4 R = *reinterpret_cast<const float4*>(src + x4 + 4);
        s6 = R.x; s7 = R.y;
    } else {
        s6 = M.z; s7 = M.y;
    }
    float s[8] = {s0, s1, M.x, M.y, M.z, M.w, s6, s7};

    const float* fb = filt + (size_t)g * KK * HW + (size_t)y * W + x4;
    float4 acc = make_float4(0.f, 0.f, 0.f, 0.f);
#pragma unroll
    for (int k = 0; k < KK; k++) {
        float4 f = *reinterpret_cast<const float4*>(fb + (size_t)k * HW);
        acc.x += s[k] * f.x;
        acc.y += s[k + 1] * f.y;
        acc.z += s[k + 2] * f.z;
        acc.w += s[k + 3] * f.w;
    }
    *reinterpret_cast<float4*>(out1 + (((size_t)n * C + c) * H + y) * W + x4) = acc;

    float ss = acc.x * acc.x + acc.y * acc.y + acc.z * acc.z + acc.w * acc.w;
#pragma unroll
    for (int off = 32; off; off >>= 1) ss += __shfl_down(ss, off);
    __shared__ float wred[4];
    if ((t & 63) == 0) wred[t >> 6] = ss;
    __syncthreads();
    if (t == 0) part[bid] = wred[0] + wred[1] + wred[2] + wred[3];
}

// ---------------- vertical strip conv (float4 sliding window) + affine ----------------
__global__ __launch_bounds__(256) void convv_kernel(const float* __restrict__ out1,
                                                    const float* __restrict__ filt,
                                                    const float* __restrict__ x,
                                                    const float* __restrict__ gamma,
                                                    const float* __restrict__ beta,
                                                    float* __restrict__ out) {
    int bid = blockIdx.x;
    int yc = bid & 3;
    int c = (bid >> 2) & (C - 1);
    int n = bid >> 8;
    int g = c >> 5;
    int t = threadIdx.x;
    int x4 = (t & 63) * 4;
    int ys = yc * 64 + (t >> 6) * 16;

    const float* plane = out1 + ((size_t)n * C + c) * HW;
    float4 win[KK];
#pragma unroll
    for (int i = 0; i < 4; i++) {
        int yy = ys - 2 + i;
        yy = yy < 0 ? -yy : yy;
        win[i] = *reinterpret_cast<const float4*>(plane + (size_t)yy * W + x4);
    }
    float gm = gamma[c], bt = beta[c];
    const float* fgb = filt + (size_t)g * KK * HW;
    for (int dy = 0; dy < 16; dy++) {
        int y = ys + dy;
        int yy = y + 2;
        yy = (yy >= H) ? (2 * H - 2 - yy) : yy;
        win[4] = *reinterpret_cast<const float4*>(plane + (size_t)yy * W + x4);
        const float* fb = fgb + (size_t)y * W + x4;
        float4 acc = make_float4(0.f, 0.f, 0.f, 0.f);
#pragma unroll
        for (int k = 0; k < KK; k++) {
            float4 f = *reinterpret_cast<const float4*>(fb + (size_t)k * HW);
            acc.x += win[k].x * f.x;
            acc.y += win[k].y * f.y;
            acc.z += win[k].z * f.z;
            acc.w += win[k].w * f.w;
        }
        size_t idx = (((size_t)n * C + c) * H + y) * W + x4;
        float4 xv = *reinterpret_cast<const float4*>(x + idx);
        float4 o;
        o.x = gm * acc.x + bt * xv.x;
        o.y = gm * acc.y + bt * xv.y;
        o.z = gm * acc.z + bt * xv.z;
        o.w = gm * acc.w + bt * xv.w;
        *reinterpret_cast<float4*>(out + idx) = o;
#pragma unroll
        for (int k = 0; k < 4; k++) win[k] = win[k + 1];
    }
}

extern "C" void kernel_launch(void* const* d_in, const int* in_sizes, int n_in,
                              void* d_out, int out_size, void* d_ws, size_t ws_size,
                              hipStream_t stream) {
    const float* x      = (const float*)d_in[0];
    const float* conv_h = (const float*)d_in[1];
    const float* conv_w = (const float*)d_in[2];
    const float* rv_h   = (const float*)d_in[3];
    const float* rv_w   = (const float*)d_in[4];
    const float* gamma  = (const float*)d_in[5];
    const float* beta   = (const float*)d_in[6];
    float* out = (float*)d_out;

    char* w = (char*)d_ws;
    size_t off = 0;
    float* out1   = (float*)(w + off); off += (size_t)NB * C * HW * 4;
    float* filtU  = (float*)(w + off); off += (size_t)HW * 12 * 4;
    float* filt   = (float*)(w + off); off += (size_t)NH * HW * 4;
    int*   dec    = (int*)  (w + off); off += (size_t)HW * 4;
    int*   order  = (int*)  (w + off); off += (size_t)HW * 4;
    int*   hist   = (int*)  (w + off); off += (size_t)NCHUNK * NBINS * 4;
    int*   bintot = (int*)  (w + off); off += 4096;
    float* part1  = (float*)(w + off); off += (size_t)NB * 256 * 4;
    float* part2  = (float*)(w + off); off += (size_t)NB * 4096 * 4;

    // ---------------- pass 1: horizontal ----------------
    sumsq_kernel<<<NB * 256, 256, 0, stream>>>(x, part1);
    hash_kernel<<<NCHUNK, 256, 0, stream>>>(x, part1, 256, rv_h, conv_h, filtU, dec, hist);
    scan1_kernel<<<NBINS / 4, 256, 0, stream>>>(hist, bintot);
    scatter_kernel<<<NCHUNK, 256, 0, stream>>>(dec, hist, bintot, order);
    filtsig_kernel<<<HW / 256, 256, 0, stream>>>(filtU, order, filt);
    convh_kernel<<<NB * C * (H / 4), 256, 0, stream>>>(x, filt, out1, part2);

    // ---------------- pass 2: vertical + affine ----------------
    hash_kernel<<<NCHUNK, 256, 0, stream>>>(out1, part2, 4096, rv_w, conv_w, filtU, dec, hist);
    scan1_kernel<<<NBINS / 4, 256, 0, stream>>>(hist, bintot);
    scatter_kernel<<<NCHUNK, 256, 0, stream>>>(dec, hist, bintot, order);
    filtsig_kernel<<<HW / 256, 256, 0, stream>>>(filtU, order, filt);
    convv_kernel<<<NB * C * (H / 64), 256, 0, stream>>>(out1, filt, x, gamma, beta, out);
}

// Round 6
// 149.032 us; speedup vs baseline: 1.6403x; 1.0163x over previous
//
#include <hip/hip_runtime.h>

#define NB 4
#define C 64
#define H 256
#define W 256
#define HW (H * W)
#define NH 10
#define KK 5
#define NBINS 1024
#define CHUNK 256
#define NCHUNK (HW / CHUNK)

// ---------------- per-batch sum of squares (256 partials per batch) ----------------
__global__ __launch_bounds__(256) void sumsq_kernel(const float* __restrict__ x,
                                                    float* __restrict__ part) {
    int bid = blockIdx.x;
    int b = bid >> 8, ch = bid & 255;
    const float4* p = reinterpret_cast<const float4*>(x + (size_t)b * C * HW) + (size_t)ch * 4096;
    float s = 0.f;
    for (int i = threadIdx.x; i < 4096; i += 256) {
        float4 v = p[i];
        s += v.x * v.x + v.y * v.y + v.z * v.z + v.w * v.w;
    }
    __shared__ float red[256];
    red[threadIdx.x] = s;
    __syncthreads();
    for (int off = 128; off; off >>= 1) {
        if (threadIdx.x < off) red[threadIdx.x] += red[threadIdx.x + off];
        __syncthreads();
    }
    if (threadIdx.x == 0) part[bid] = red[0];
}

// ---------------- LSH + conv projections of best plane + per-chunk histogram ----------------
// Fused argmax: every block redundantly reduces `part` (float4 loads) for the best batch.
__global__ __launch_bounds__(256) void hash_kernel(const float* __restrict__ Xall,
                                                   const float* __restrict__ part,
                                                   int per_batch,
                                                   const float* __restrict__ rvecs,
                                                   const float* __restrict__ cwg,
                                                   float* __restrict__ filtU,
                                                   int* __restrict__ dec,
                                                   int* __restrict__ hist) {
    __shared__ float tile[CHUNK][33];
    __shared__ float rv[NH * C];
    __shared__ float cw[NH * C];
    __shared__ int lhist[NBINS];
    __shared__ float4 red4[256];
    int t = threadIdx.x;
    for (int i = t; i < NH * C; i += 256) { rv[i] = rvecs[i]; cw[i] = cwg[i]; }
    for (int i = t; i < NBINS; i += 256) lhist[i] = 0;

    // redundant per-block argmax over batch norms (vectorized partial read)
    float4 ss = make_float4(0.f, 0.f, 0.f, 0.f);
    int q4 = per_batch >> 2;
    for (int i = t; i < q4; i += 256) {
        float4 a = *reinterpret_cast<const float4*>(part + 0 * per_batch + i * 4);
        float4 b = *reinterpret_cast<const float4*>(part + 1 * per_batch + i * 4);
        float4 c = *reinterpret_cast<const float4*>(part + 2 * per_batch + i * 4);
        float4 d = *reinterpret_cast<const float4*>(part + 3 * per_batch + i * 4);
        ss.x += a.x + a.y + a.z + a.w;
        ss.y += b.x + b.y + b.z + b.w;
        ss.z += c.x + c.y + c.z + c.w;
        ss.w += d.x + d.y + d.z + d.w;
    }
    red4[t] = ss;
    __syncthreads();
    for (int off = 128; off; off >>= 1) {
        if (t < off) {
            red4[t].x += red4[t + off].x;
            red4[t].y += red4[t + off].y;
            red4[t].z += red4[t + off].z;
            red4[t].w += red4[t + off].w;
        }
        __syncthreads();
    }
    float4 nm = red4[0];
    float nv[NB] = {nm.x, nm.y, nm.z, nm.w};
    int best = 0;
    float m = nv[0];
#pragma unroll
    for (int i = 1; i < NB; i++)
        if (nv[i] > m) { m = nv[i]; best = i; }

    const float* X = Xall + (size_t)best * C * HW;
    int p0 = blockIdx.x * CHUNK;
    float acc[NH], cacc[NH];
#pragma unroll
    for (int h2 = 0; h2 < NH; h2++) { acc[h2] = 0.f; cacc[h2] = 0.f; }

    for (int half = 0; half < 2; half++) {
        __syncthreads();
        for (int c = 0; c < 32; c++) tile[t][c] = X[(size_t)(half * 32 + c) * HW + p0 + t];
        __syncthreads();
        for (int c = 0; c < 32; c += 4) {
            float4 v = make_float4(tile[t][c], tile[t][c + 1], tile[t][c + 2], tile[t][c + 3]);
#pragma unroll
            for (int h2 = 0; h2 < NH; h2++) {
                const float* r = rv + h2 * C + half * 32 + c;
                const float* cc = cw + h2 * C + half * 32 + c;
                acc[h2] += v.x * r[0] + v.y * r[1] + v.z * r[2] + v.w * r[3];
                cacc[h2] += v.x * cc[0] + v.y * cc[1] + v.z * cc[2] + v.w * cc[3];
            }
        }
    }
    int d = 0;
#pragma unroll
    for (int h2 = 0; h2 < NH; h2++) d |= (acc[h2] > 0.f) ? (1 << h2) : 0;
    dec[p0 + t] = d;
    atomicAdd(&lhist[d], 1);

    float* fu = filtU + (size_t)(p0 + t) * 12;
    float s01 = 1.f / (1.f + expf(-cacc[0])), s1 = 1.f / (1.f + expf(-cacc[1]));
    float s2 = 1.f / (1.f + expf(-cacc[2])), s3 = 1.f / (1.f + expf(-cacc[3]));
    float s4 = 1.f / (1.f + expf(-cacc[4])), s5 = 1.f / (1.f + expf(-cacc[5]));
    float s6 = 1.f / (1.f + expf(-cacc[6])), s7 = 1.f / (1.f + expf(-cacc[7]));
    float s8 = 1.f / (1.f + expf(-cacc[8])), s9 = 1.f / (1.f + expf(-cacc[9]));
    *reinterpret_cast<float4*>(fu + 0) = make_float4(s01, s1, s2, s3);
    *reinterpret_cast<float4*>(fu + 4) = make_float4(s4, s5, s6, s7);
    *reinterpret_cast<float4*>(fu + 8) = make_float4(s8, s9, 0.f, 0.f);

    __syncthreads();
    for (int i = t; i < NBINS; i += 256) hist[(size_t)i * NCHUNK + blockIdx.x] = lhist[i];
}

// ---------------- parallel per-bin chunk scan: one bin per wave ----------------
__global__ __launch_bounds__(256) void scan1_kernel(int* __restrict__ hist,
                                                    int* __restrict__ bintot) {
    int t = threadIdx.x;
    int lane = t & 63;
    int b = blockIdx.x * 4 + (t >> 6);
    int4 v = *reinterpret_cast<int4*>(hist + (size_t)b * NCHUNK + lane * 4);
    int s0 = v.x;
    int s1 = s0 + v.y;
    int s2 = s1 + v.z;
    int s3 = s2 + v.w;
    int s = s3;
#pragma unroll
    for (int off = 1; off < 64; off <<= 1) {
        int nbr = __shfl_up(s, off);
        if (lane >= off) s += nbr;
    }
    int excl = s - s3;
    int4 o;
    o.x = excl;
    o.y = excl + s0;
    o.z = excl + s1;
    o.w = excl + s2;
    *reinterpret_cast<int4*>(hist + (size_t)b * NCHUNK + lane * 4) = o;
    if (lane == 63) bintot[b] = s;
}

// ---------------- stable scatter, filt written DIRECTLY at sorted position ----------------
// (binoff fused via LDS scan of bintot; filtsig kernel + order buffer eliminated)
__global__ __launch_bounds__(256) void scatter_kernel(const int* __restrict__ dec,
                                                      const int* __restrict__ hist,
                                                      const int* __restrict__ bintot,
                                                      const float* __restrict__ filtU,
                                                      float* __restrict__ filt) {
    __shared__ int boffs[NBINS];
    __shared__ int wtot[4];
    __shared__ int keys[CHUNK];
    int t = threadIdx.x;
    int lane = t & 63;
    int w = t >> 6;
    int4 v = *reinterpret_cast<const int4*>(bintot + t * 4);
    int s0 = v.x, s1 = s0 + v.y, s2 = s1 + v.z, s3 = s2 + v.w;
    int s = s3;
#pragma unroll
    for (int off = 1; off < 64; off <<= 1) {
        int nbr = __shfl_up(s, off);
        if (lane >= off) s += nbr;
    }
    int excl = s - s3;
    if (lane == 63) wtot[w] = s;
    __syncthreads();
    int wbase = 0;
#pragma unroll
    for (int i = 0; i < 4; i++) wbase += (i < w) ? wtot[i] : 0;
    boffs[t * 4 + 0] = wbase + excl;
    boffs[t * 4 + 1] = wbase + excl + s0;
    boffs[t * 4 + 2] = wbase + excl + s1;
    boffs[t * 4 + 3] = wbase + excl + s2;

    int p0 = blockIdx.x * CHUNK;
    int k = dec[p0 + t];
    keys[t] = k;
    __syncthreads();
    int r = 0;
    for (int j = 0; j < t; j++) r += (keys[j] == k) ? 1 : 0;
    int dst = boffs[k] + hist[(size_t)k * NCHUNK + blockIdx.x] + r;

    // gather this pixel's sigmoid'd projections (coalesced) and scatter to filt planes
    const float4* fu = reinterpret_cast<const float4*>(filtU + (size_t)(p0 + t) * 12);
    float4 a = fu[0], b4 = fu[1], c4 = fu[2];
    float vv[10] = {a.x, a.y, a.z, a.w, b4.x, b4.y, b4.z, b4.w, c4.x, c4.y};
#pragma unroll
    for (int h2 = 0; h2 < NH; h2++) filt[(size_t)h2 * HW + dst] = vv[h2];
}

// ---------------- horizontal strip conv (float4) + sumsq partials ----------------
__global__ __launch_bounds__(256) void convh_kernel(const float* __restrict__ X,
                                                    const float* __restrict__ filt,
                                                    float* __restrict__ out1,
                                                    float* __restrict__ part) {
    int bid = blockIdx.x;
    int rb = bid & 63;
    int c = (bid >> 6) & (C - 1);
    int n = bid >> 12;
    int g = c >> 5;
    int t = threadIdx.x;
    int x4 = (t & 63) * 4;
    int y = rb * 4 + (t >> 6);

    const float* src = X + (((size_t)n * C + c) * H + y) * W;
    float4 M = *reinterpret_cast<const float4*>(src + x4);
    float s0, s1, s6, s7;
    if (x4 > 0) {
        float4 L = *reinterpret_cast<const float4*>(src + x4 - 4);
        s0 = L.z; s1 = L.w;
    } else {
        s0 = M.z; s1 = M.y;
    }
    if (x4 < W - 4) {
        float4 R = *reinterpret_cast<const float4*>(src + x4 + 4);
        s6 = R.x; s7 = R.y;
    } else {
        s6 = M.z; s7 = M.y;
    }
    float s[8] = {s0, s1, M.x, M.y, M.z, M.w, s6, s7};

    const float* fb = filt + (size_t)g * KK * HW + (size_t)y * W + x4;
    float4 acc = make_float4(0.f, 0.f, 0.f, 0.f);
#pragma unroll
    for (int k = 0; k < KK; k++) {
        float4 f = *reinterpret_cast<const float4*>(fb + (size_t)k * HW);
        acc.x += s[k] * f.x;
        acc.y += s[k + 1] * f.y;
        acc.z += s[k + 2] * f.z;
        acc.w += s[k + 3] * f.w;
    }
    *reinterpret_cast<float4*>(out1 + (((size_t)n * C + c) * H + y) * W + x4) = acc;

    float ss = acc.x * acc.x + acc.y * acc.y + acc.z * acc.z + acc.w * acc.w;
#pragma unroll
    for (int off = 32; off; off >>= 1) ss += __shfl_down(ss, off);
    __shared__ float wred[4];
    if ((t & 63) == 0) wred[t >> 6] = ss;
    __syncthreads();
    if (t == 0) part[bid] = wred[0] + wred[1] + wred[2] + wred[3];
}

// ---------------- vertical strip conv (float4 sliding window) + affine ----------------
// TY=8: grid NB*C*8 = 2048 blocks -> 8 blocks/CU, 32 waves/CU (max occupancy)
__global__ __launch_bounds__(256) void convv_kernel(const float* __restrict__ out1,
                                                    const float* __restrict__ filt,
                                                    const float* __restrict__ x,
                                                    const float* __restrict__ gamma,
                                                    const float* __restrict__ beta,
                                                    float* __restrict__ out) {
    int bid = blockIdx.x;
    int yc = bid & 7;
    int c = (bid >> 3) & (C - 1);
    int n = bid >> 9;
    int g = c >> 5;
    int t = threadIdx.x;
    int x4 = (t & 63) * 4;
    int ys = yc * 32 + (t >> 6) * 8;

    const float* plane = out1 + ((size_t)n * C + c) * HW;
    float4 win[KK];
#pragma unroll
    for (int i = 0; i < 4; i++) {
        int yy = ys - 2 + i;
        yy = yy < 0 ? -yy : yy;
        win[i] = *reinterpret_cast<const float4*>(plane + (size_t)yy * W + x4);
    }
    float gm = gamma[c], bt = beta[c];
    const float* fgb = filt + (size_t)g * KK * HW;
    for (int dy = 0; dy < 8; dy++) {
        int y = ys + dy;
        int yy = y + 2;
        yy = (yy >= H) ? (2 * H - 2 - yy) : yy;
        win[4] = *reinterpret_cast<const float4*>(plane + (size_t)yy * W + x4);
        const float* fb = fgb + (size_t)y * W + x4;
        float4 acc = make_float4(0.f, 0.f, 0.f, 0.f);
#pragma unroll
        for (int k = 0; k < KK; k++) {
            float4 f = *reinterpret_cast<const float4*>(fb + (size_t)k * HW);
            acc.x += win[k].x * f.x;
            acc.y += win[k].y * f.y;
            acc.z += win[k].z * f.z;
            acc.w += win[k].w * f.w;
        }
        size_t idx = (((size_t)n * C + c) * H + y) * W + x4;
        float4 xv = *reinterpret_cast<const float4*>(x + idx);
        float4 o;
        o.x = gm * acc.x + bt * xv.x;
        o.y = gm * acc.y + bt * xv.y;
        o.z = gm * acc.z + bt * xv.z;
        o.w = gm * acc.w + bt * xv.w;
        *reinterpret_cast<float4*>(out + idx) = o;
#pragma unroll
        for (int k = 0; k < 4; k++) win[k] = win[k + 1];
    }
}

extern "C" void kernel_launch(void* const* d_in, const int* in_sizes, int n_in,
                              void* d_out, int out_size, void* d_ws, size_t ws_size,
                              hipStream_t stream) {
    const float* x      = (const float*)d_in[0];
    const float* conv_h = (const float*)d_in[1];
    const float* conv_w = (const float*)d_in[2];
    const float* rv_h   = (const float*)d_in[3];
    const float* rv_w   = (const float*)d_in[4];
    const float* gamma  = (const float*)d_in[5];
    const float* beta   = (const float*)d_in[6];
    float* out = (float*)d_out;

    char* w = (char*)d_ws;
    size_t off = 0;
    float* out1   = (float*)(w + off); off += (size_t)NB * C * HW * 4;
    float* filtU  = (float*)(w + off); off += (size_t)HW * 12 * 4;
    float* filt   = (float*)(w + off); off += (size_t)NH * HW * 4;
    int*   dec    = (int*)  (w + off); off += (size_t)HW * 4;
    int*   hist   = (int*)  (w + off); off += (size_t)NCHUNK * NBINS * 4;
    int*   bintot = (int*)  (w + off); off += 4096;
    float* part1  = (float*)(w + off); off += (size_t)NB * 256 * 4;
    float* part2  = (float*)(w + off); off += (size_t)NB * 4096 * 4;

    // ---------------- pass 1: horizontal ----------------
    sumsq_kernel<<<NB * 256, 256, 0, stream>>>(x, part1);
    hash_kernel<<<NCHUNK, 256, 0, stream>>>(x, part1, 256, rv_h, conv_h, filtU, dec, hist);
    scan1_kernel<<<NBINS / 4, 256, 0, stream>>>(hist, bintot);
    scatter_kernel<<<NCHUNK, 256, 0, stream>>>(dec, hist, bintot, filtU, filt);
    convh_kernel<<<NB * C * (H / 4), 256, 0, stream>>>(x, filt, out1, part2);

    // ---------------- pass 2: vertical + affine ----------------
    hash_kernel<<<NCHUNK, 256, 0, stream>>>(out1, part2, 4096, rv_w, conv_w, filtU, dec, hist);
    scan1_kernel<<<NBINS / 4, 256, 0, stream>>>(hist, bintot);
    scatter_kernel<<<NCHUNK, 256, 0, stream>>>(dec, hist, bintot, filtU, filt);
    convv_kernel<<<NB * C * 8, 256, 0, stream>>>(out1, filt, x, gamma, beta, out);
}